// Round 10
// baseline (1021.152 us; speedup 1.0000x reference)
//
#include <hip/hip_runtime.h>

#define KK 32
#define KP 33
#define NMAXC 256
#define BCH 32            // bsz * ENS
#define NPADC 32768
#define TARGETC 32640
#define LSEG 64           // items per segment
#define MSEG 512          // NPADC / LSEG
#define GSZ 32            // segments per group
#define NG 16             // MSEG / GSZ
#define SS 2
#define NBLK 1024         // persistent grid: 4 blocks/CU x 256 CUs
#define NSLOT 4096        // NBLK * 4 waves

#define OFFS(i) ((i)*255 - (i)*((i)-1)/2)

// ---- cross-lane helpers on the VALU pipe (no ds_bpermute) ----
__device__ __forceinline__ int dpp_shr1_i(int v) {
    return __builtin_amdgcn_mov_dpp(v, 0x138, 0xf, 0xf, true);  // wave_shr:1, bc=1
}
__device__ __forceinline__ double dpp_shr1_d(double v) {
    union { double d; int i[2]; } u; u.d = v;
    u.i[0] = dpp_shr1_i(u.i[0]);
    u.i[1] = dpp_shr1_i(u.i[1]);
    return u.d;
}
__device__ __forceinline__ double readlane_d(double v, int l) {
    union { double d; int i[2]; } u; u.d = v;
    union { double d; int i[2]; } r;
    r.i[0] = __builtin_amdgcn_readlane(u.i[0], l);
    r.i[1] = __builtin_amdgcn_readlane(u.i[1], l);
    return r.d;
}
__device__ __forceinline__ double readlane_f_to_d(float v, int l) {
    union { float f; int i; } u; u.f = v;
    union { float f; int i; } r;
    r.i = __builtin_amdgcn_readlane(u.i, l);
    return (double)r.f;
}

__device__ __forceinline__ void decode_ij(int t, int& oi, int& oj) {
    int ii = (int)((511.0 - sqrt(511.0 * 511.0 - 8.0 * (double)t)) * 0.5);
    if (ii < 0) ii = 0;
    if (ii > 254) ii = 254;
    while (ii < 254 && OFFS(ii + 1) <= t) ++ii;
    while (ii > 0 && OFFS(ii) > t) --ii;
    oi = ii;
    oj = t - OFFS(ii) + ii + 1;
}

// 33-point truncated polynomial product: out[r] = sum_j a[j]*b[r-j].
__device__ __forceinline__ double conv33_rb(double a_dep, double b_rot) {
    double s0 = 0.0, s1 = 0.0, s2 = 0.0, s3 = 0.0;
    double brot = b_rot;
#pragma unroll
    for (int j = 0; j < KP; ++j) {
        double aj = readlane_d(a_dep, j);
        switch (j & 3) {
            case 0: s0 = fma(aj, brot, s0); break;
            case 1: s1 = fma(aj, brot, s1); break;
            case 2: s2 = fma(aj, brot, s2); break;
            default: s3 = fma(aj, brot, s3); break;
        }
        brot = dpp_shr1_d(brot);
    }
    return (s0 + s1) + (s2 + s3);
}

// ---- grid barrier: 32-leaf arrival tree + generation flag, agent scope ----
__device__ __forceinline__ void gridbar(int* bars, int idx) {
    __syncthreads();
    if (threadIdx.x == 0) {
        int* gen  = bars + idx;                                   // 6 gens, one line
        int* leaf = bars + 16 + idx * 512 + (blockIdx.x & 31) * 16;  // 64B stride
        int* root = bars + 16 + 6 * 512 + idx * 16;
        int g = __hip_atomic_load(gen, __ATOMIC_RELAXED, __HIP_MEMORY_SCOPE_AGENT);
        __threadfence();                                          // release our data
        if (__hip_atomic_fetch_add(leaf, 1, __ATOMIC_ACQ_REL, __HIP_MEMORY_SCOPE_AGENT) == 31) {
            if (__hip_atomic_fetch_add(root, 1, __ATOMIC_ACQ_REL, __HIP_MEMORY_SCOPE_AGENT) == 31) {
                __hip_atomic_fetch_add(gen, 1, __ATOMIC_ACQ_REL, __HIP_MEMORY_SCOPE_AGENT);
            }
        }
        long sp = 0;
        while (__hip_atomic_load(gen, __ATOMIC_ACQUIRE, __HIP_MEMORY_SCOPE_AGENT) == g) {
            __builtin_amdgcn_s_sleep(8);
            if (++sp > (1L << 22)) break;                         // safety valve
        }
        __threadfence();                                          // acquire
    }
    __syncthreads();
}

__global__ void __launch_bounds__(256, 4)
k_all(const float* __restrict__ sc, const float* __restrict__ U,
      double* __restrict__ X, double* __restrict__ Bp, double* __restrict__ sfxI,
      double* __restrict__ gpoly, double* __restrict__ gcarry, double* __restrict__ eZ,
      unsigned long long* __restrict__ masks, int* __restrict__ tab,
      int* __restrict__ rent, unsigned long long* __restrict__ bitflat,
      float* __restrict__ outMask, float* __restrict__ outMarg, int* __restrict__ bars) {
    __shared__ union {
        struct { int gtab[NG][KP]; int gent[NG]; } c;
        unsigned long long bf[MSEG];
        struct { double e[KP]; double invZ; } mg;
    } sm;
    int tid = threadIdx.x;
    int lane = tid & 63;
    int wslot = blockIdx.x * 4 + (tid >> 6);       // 0..4095

    // ---- phase 1: prep (exp(theta) + per-segment polys) ----
    for (int blk = wslot; blk < BCH * MSEG; blk += NSLOT) {
        int b = blk >> 9, m = blk & (MSEG - 1);
        int t = m * LSEG + lane;
        double x = 0.0;
        if (t < TARGETC) {
            int i, j;
            decode_ij(t, i, j);
            double th = (double)sc[((size_t)b * NMAXC + i) * NMAXC + j] +
                        (double)sc[((size_t)b * NMAXC + j) * NMAXC + i];
            x = exp(th);
        }
        X[(size_t)b * NPADC + t] = x;
        double c = (lane == 0) ? 1.0 : 0.0;
#pragma unroll
        for (int j = 0; j < LSEG; ++j) {
            double xj = readlane_d(x, j);
            double up = dpp_shr1_d(c);
            c = fma(xj, up, c);
        }
        if (lane < KP) Bp[(size_t)blk * KP + lane] = c;
    }
    gridbar(bars, 0);

    // ---- phase 2: suffix-inclusive scan within group ----
    if (wslot < BCH * NG) {
        int b = wslot / NG, g = wslot % NG;
        double run = (lane == 0) ? 1.0 : 0.0;
        int m0 = g * GSZ + (GSZ - 1);
        double bp = (lane < KP) ? Bp[((size_t)b * MSEG + m0) * KP + lane] : 0.0;
        for (int i = GSZ - 1; i >= 0; --i) {
            int mi = g * GSZ + i;
            double bpn = (i > 0 && lane < KP) ? Bp[((size_t)b * MSEG + mi - 1) * KP + lane] : 0.0;
            run = conv33_rb(run, bp);
            if (lane < KP) sfxI[((size_t)b * MSEG + mi) * KP + lane] = run;
            bp = bpn;
        }
        if (lane < KP) gpoly[(size_t)wslot * KP + lane] = run;
    }
    gridbar(bars, 1);

    // ---- phase 3: suffix scan over group polys + full Z poly ----
    if (wslot < BCH) {
        int b = wslot;
        double run = (lane == 0) ? 1.0 : 0.0;
        double gp = (lane < KP) ? gpoly[((size_t)b * NG + NG - 1) * KP + lane] : 0.0;
        for (int g = NG - 1; g >= 0; --g) {
            if (lane < KP) gcarry[((size_t)b * NG + g) * KP + lane] = run;
            double gpn = (g > 0 && lane < KP) ? gpoly[((size_t)b * NG + g - 1) * KP + lane] : 0.0;
            run = conv33_rb(run, gp);
            gp = gpn;
        }
        if (lane < KP) eZ[(size_t)b * KP + lane] = run;
    }
    gridbar(bars, 2);

    // ---- phase 4: backward sfx sweep + sampling (chkpt fused) ----
    for (int blk = wslot; blk < BCH * MSEG; blk += NSLOT) {
        int b = blk >> 9, m = blk & (MSEG - 1);
        double xa = X[(size_t)b * NPADC + (size_t)m * LSEG + lane];
        float uf0 = U[((size_t)0 * NPADC + (size_t)m * LSEG + lane) * BCH + b];
        float uf1 = U[((size_t)1 * NPADC + (size_t)m * LSEG + lane) * BCH + b];
        double c;
        if (m + 1 == MSEG) {
            c = (lane == 0) ? 1.0 : 0.0;
        } else {
            double a  = (lane < KP) ? sfxI[((size_t)b * MSEG + m + 1) * KP + lane] : 0.0;
            double cg = (lane < KP) ? gcarry[((size_t)b * NG + (m + 1) / GSZ) * KP + lane] : 0.0;
            c = conv33_rb(cg, a);
            c = (lane < KP) ? c : 0.0;
        }
        int S0 = lane, S1 = lane;
        unsigned long long mk0 = 0, mk1 = 0;
#pragma unroll
        for (int j = LSEG - 1; j >= 0; --j) {
            double xj = readlane_d(xa, j);
            double up = dpp_shr1_d(c);
            double rhs = xj * up;
            double cn = fma(xj, up, c);
            double ud0 = readlane_f_to_d(uf0, j);
            double ud1 = readlane_f_to_d(uf1, j);
            bool i0 = (ud0 * cn < rhs);
            bool i1 = (ud1 * cn < rhs);
            unsigned long long b0 = __ballot(i0);
            unsigned long long b1 = __ballot(i1);
            if (lane == j) { mk0 = b0; mk1 = b1; }
            int t0 = dpp_shr1_i(S0);
            int t1 = dpp_shr1_i(S1);
            if (i0) S0 = t0;
            if (i1) S1 = t1;
            c = cn;
        }
        size_t sb0 = (size_t)blk;
        size_t sb1 = (size_t)BCH * MSEG + blk;
        masks[sb0 * LSEG + lane] = mk0;
        masks[sb1 * LSEG + lane] = mk1;
        if (lane < KP) {
            tab[sb0 * KP + lane] = S0;
            tab[sb1 * KP + lane] = S1;
        }
    }
    gridbar(bars, 3);

    // ---- phase 5: hierarchical compose (one block per chain sb) ----
    if (blockIdx.x < SS * BCH) {
        int sb = blockIdx.x;
        int w4 = tid >> 6;
        for (int q = 0; q < 4; ++q) {
            int g = w4 * 4 + q;
            const int* base = tab + ((size_t)sb * MSEG + g * GSZ) * KP;
            int tv[GSZ];
#pragma unroll
            for (int i = 0; i < GSZ; ++i)
                tv[i] = (lane < KP) ? base[i * KP + lane] : 0;
            int T = lane;
#pragma unroll
            for (int i = 0; i < GSZ; ++i)
                T = __shfl(tv[i], T, 64);
            if (lane < KP) sm.c.gtab[g][lane] = T;
        }
        __syncthreads();
        if (tid == 0) {
            int r = KK;
            for (int g = 0; g < NG; ++g) { sm.c.gent[g] = r; r = sm.c.gtab[g][r]; }
        }
        __syncthreads();
        for (int q = 0; q < 4; ++q) {
            int g = w4 * 4 + q;
            const int* base = tab + ((size_t)sb * MSEG + g * GSZ) * KP;
            int tv[GSZ];
#pragma unroll
            for (int i = 0; i < GSZ; ++i)
                tv[i] = (lane < KP) ? base[i * KP + lane] : 0;
            int r = __builtin_amdgcn_readfirstlane(sm.c.gent[g]);
            int rv = 0;
#pragma unroll
            for (int i = 0; i < GSZ; ++i) {
                if (lane == i) rv = r;
                r = __builtin_amdgcn_readlane(tv[i], r);
            }
            if (lane < GSZ) rent[(size_t)sb * MSEG + g * GSZ + lane] = rv;
        }
    }
    gridbar(bars, 4);

    // ---- phase 6: replay masks along realized path -> packed bitset ----
    for (int blk = wslot; blk < SS * BCH * MSEG; blk += NSLOT) {
        unsigned long long mv = masks[(size_t)blk * LSEG + lane];
        int mlo = (int)(unsigned)mv;
        int mhi = (int)(unsigned)(mv >> 32);
        int r = __builtin_amdgcn_readfirstlane(rent[blk]);
        unsigned long long sel = 0;
#pragma unroll
        for (int j = 0; j < LSEG; ++j) {
            unsigned lo = (unsigned)__builtin_amdgcn_readlane(mlo, j);
            unsigned hi = (unsigned)__builtin_amdgcn_readlane(mhi, j);
            unsigned long long mj = ((unsigned long long)hi << 32) | lo;
            int inc = (int)((mj >> r) & 1ull);
            sel |= ((unsigned long long)inc) << j;
            r -= inc;
        }
        if (lane == 0) bitflat[blk] = sel;
    }
    gridbar(bars, 5);

    // ---- phase 7: output emission (mask rows then marginal rows) ----
    for (int bt = blockIdx.x; bt < (SS * BCH + BCH) * NMAXC; bt += NBLK) {
        int y = bt >> 8;
        int i = bt & (NMAXC - 1);
        int j = tid;
        if (y < SS * BCH) {
            int sb = y;
            sm.bf[j] = bitflat[(size_t)sb * MSEG + j];
            sm.bf[j + 256] = bitflat[(size_t)sb * MSEG + 256 + j];
            __syncthreads();
            float v = 0.0f;
            if (j > i) {
                int t = OFFS(i) + j - i - 1;
                v = (float)((sm.bf[t >> 6] >> (t & 63)) & 1ull);
            } else if (j < i) {
                int t = OFFS(j) + i - j - 1;
                v = (float)((sm.bf[t >> 6] >> (t & 63)) & 1ull);
            }
            outMask[((size_t)sb * NMAXC + i) * NMAXC + j] = v;
        } else {
            int b = y - SS * BCH;
            if (j < KP) sm.mg.e[j] = eZ[(size_t)b * KP + j];
            __syncthreads();
            if (j == 0) sm.mg.invZ = 1.0 / sm.mg.e[KK];
            __syncthreads();
            float v = 0.0f;
            if (i != j) {
                int t = (j > i) ? (OFFS(i) + j - i - 1) : (OFFS(j) + i - j - 1);
                double x = X[(size_t)b * NPADC + t];
                double f = 1.0;
#pragma unroll
                for (int k = 1; k < KK; ++k) f = fma(-x, f, sm.mg.e[k]);
                v = (float)(x * f * sm.mg.invZ);
            }
            outMarg[((size_t)b * NMAXC + i) * NMAXC + j] = v;
        }
        __syncthreads();   // protect LDS reuse across grid-stride iterations
    }
}

extern "C" void kernel_launch(void* const* d_in, const int* in_sizes, int n_in,
                              void* d_out, int out_size, void* d_ws, size_t ws_size,
                              hipStream_t stream) {
    const float* scores = (const float*)d_in[0];
    const float* uniforms = (const float*)d_in[1];

    char* ws = (char*)d_ws;
    size_t off = 0;
    auto alloc = [&](size_t bytes) {
        void* p = ws + off;
        off += (bytes + 255) & ~(size_t)255;
        return p;
    };
    int*    bars   = (int*)alloc(16384);   // barrier gens + leaf/root counters
    double* X      = (double*)alloc((size_t)BCH * NPADC * 8);
    double* Bp     = (double*)alloc((size_t)BCH * MSEG * KP * 8);
    double* sfxI   = (double*)alloc((size_t)BCH * MSEG * KP * 8);
    double* gpoly  = (double*)alloc((size_t)BCH * NG * KP * 8);
    double* gcarry = (double*)alloc((size_t)BCH * NG * KP * 8);
    double* eZ     = (double*)alloc((size_t)BCH * KP * 8);
    unsigned long long* masks = (unsigned long long*)alloc((size_t)SS * BCH * MSEG * LSEG * 8);
    int* tab       = (int*)alloc((size_t)SS * BCH * MSEG * KP * 4);
    int* rent      = (int*)alloc((size_t)SS * BCH * MSEG * 4);
    unsigned long long* bitflat = (unsigned long long*)alloc((size_t)SS * BCH * MSEG * 8);
    if (off > ws_size) return;            // ~38 MB

    hipMemsetAsync(bars, 0, 16384, stream);
    k_all<<<NBLK, 256, 0, stream>>>(
        scores, uniforms, X, Bp, sfxI, gpoly, gcarry, eZ, masks, tab, rent, bitflat,
        (float*)d_out, (float*)d_out + (size_t)SS * BCH * NMAXC * NMAXC, bars);
}

// Round 11
// 156.852 us; speedup vs baseline: 6.5103x; 6.5103x over previous
//
#include <hip/hip_runtime.h>

#define KK 32
#define KP 33
#define NMAXC 256
#define BCH 32            // bsz * ENS
#define NPADC 32768
#define TARGETC 32640
#define LSEG 64           // items per segment
#define MSEG 512          // NPADC / LSEG
#define GSZ 32            // segments per group
#define NG 16             // MSEG / GSZ
#define SS 2

#define OFFS(i) ((i)*255 - (i)*((i)-1)/2)

// ---- cross-lane helpers on the VALU pipe (no ds_bpermute) ----
__device__ __forceinline__ int dpp_shr1_i(int v) {
    // wave_shr:1 (0x138), bound_ctrl=1 -> lane 0 receives 0
    return __builtin_amdgcn_mov_dpp(v, 0x138, 0xf, 0xf, true);
}
__device__ __forceinline__ double dpp_shr1_d(double v) {
    union { double d; int i[2]; } u; u.d = v;
    u.i[0] = dpp_shr1_i(u.i[0]);
    u.i[1] = dpp_shr1_i(u.i[1]);
    return u.d;
}
__device__ __forceinline__ double readlane_d(double v, int l) {
    union { double d; int i[2]; } u; u.d = v;
    union { double d; int i[2]; } r;
    r.i[0] = __builtin_amdgcn_readlane(u.i[0], l);
    r.i[1] = __builtin_amdgcn_readlane(u.i[1], l);
    return r.d;
}

__device__ __forceinline__ void decode_ij(int t, int& oi, int& oj) {
    int ii = (int)((511.0 - sqrt(511.0 * 511.0 - 8.0 * (double)t)) * 0.5);
    if (ii < 0) ii = 0;
    if (ii > 254) ii = 254;
    while (ii < 254 && OFFS(ii + 1) <= t) ++ii;
    while (ii > 0 && OFFS(ii) > t) --ii;
    oi = ii;
    oj = t - OFFS(ii) + ii + 1;
}

// 33-point truncated polynomial product: out[r] = sum_j a[j]*b[r-j].
// a read via readlane (dependent operand), b rotated via DPP (independent).
__device__ __forceinline__ double conv33_rb(double a_dep, double b_rot) {
    double s0 = 0.0, s1 = 0.0, s2 = 0.0, s3 = 0.0;
    double brot = b_rot;
#pragma unroll
    for (int j = 0; j < KP; ++j) {
        double aj = readlane_d(a_dep, j);
        switch (j & 3) {
            case 0: s0 = fma(aj, brot, s0); break;
            case 1: s1 = fma(aj, brot, s1); break;
            case 2: s2 = fma(aj, brot, s2); break;
            default: s3 = fma(aj, brot, s3); break;
        }
        brot = dpp_shr1_d(brot);
    }
    return (s0 + s1) + (s2 + s3);
}

// ---- kernel 1: fused exp(theta) + per-segment elementary symmetric polys
__global__ void k_prep(const float* __restrict__ sc, double* __restrict__ X,
                       double* __restrict__ Bp) {
    int lane = threadIdx.x & 63;
    int blk = blockIdx.x * 4 + (threadIdx.x >> 6);   // b*MSEG + m
    int b = blk >> 9, m = blk & (MSEG - 1);
    int t = m * LSEG + lane;
    double x = 0.0;
    if (t < TARGETC) {
        int i, j;
        decode_ij(t, i, j);
        double th = (double)sc[((size_t)b * NMAXC + i) * NMAXC + j] +
                    (double)sc[((size_t)b * NMAXC + j) * NMAXC + i];
        x = exp(th);
    }
    X[(size_t)b * NPADC + t] = x;
    double c = (lane == 0) ? 1.0 : 0.0;
#pragma unroll
    for (int j = 0; j < LSEG; ++j) {
        double xj = readlane_d(x, j);
        double up = dpp_shr1_d(c);                   // lane0 -> 0
        c = fma(xj, up, c);
    }
    if (lane < KP) Bp[(size_t)blk * KP + lane] = c;
}

// ---- kernel 2: suffix-inclusive scan within group (1 wave/block, 512 blocks)
__global__ void k_gpart(const double* __restrict__ Bp,
                        double* __restrict__ sfxI, double* __restrict__ gpoly) {
    int lane = threadIdx.x;
    int blk = blockIdx.x;                 // b*NG + g
    int b = blk / NG, g = blk % NG;
    double run = (lane == 0) ? 1.0 : 0.0;
    int m = g * GSZ + (GSZ - 1);
    double bp = (lane < KP) ? Bp[((size_t)b * MSEG + m) * KP + lane] : 0.0;
    for (int i = GSZ - 1; i >= 0; --i) {
        int mi = g * GSZ + i;
        double bpn = (i > 0 && lane < KP) ? Bp[((size_t)b * MSEG + mi - 1) * KP + lane] : 0.0;
        run = conv33_rb(run, bp);         // dependent operand via readlane
        if (lane < KP) sfxI[((size_t)b * MSEG + mi) * KP + lane] = run;
        bp = bpn;
    }
    if (lane < KP) gpoly[(size_t)blk * KP + lane] = run;
}

// ---- kernel 3: suffix scan over group polys (exclusive carries) + full Z poly
__global__ void k_gscan(const double* __restrict__ gpoly, double* __restrict__ gcarry,
                        double* __restrict__ eZ) {
    int lane = threadIdx.x;
    int b = blockIdx.x;
    double run = (lane == 0) ? 1.0 : 0.0;
    double gp = (lane < KP) ? gpoly[((size_t)b * NG + NG - 1) * KP + lane] : 0.0;
    for (int g = NG - 1; g >= 0; --g) {
        if (lane < KP) gcarry[((size_t)b * NG + g) * KP + lane] = run;
        double gpn = (g > 0 && lane < KP) ? gpoly[((size_t)b * NG + g - 1) * KP + lane] : 0.0;
        run = conv33_rb(run, gp);
        gp = gpn;
    }
    if (lane < KP) eZ[(size_t)b * KP + lane] = run;   // e_0..e_K of all items
}

// ---- kernel 4: backward sfx sweep fused with sampling; entry checkpoint
//      reconstructed in-kernel. u pre-converted to f64 once per lane.
__global__ void k_backward(const double* __restrict__ X, const double* __restrict__ sfxI,
                           const double* __restrict__ gcarry, const float* __restrict__ U,
                           unsigned long long* __restrict__ masks, int* __restrict__ tab) {
    int lane = threadIdx.x & 63;
    int blk = blockIdx.x * 4 + (threadIdx.x >> 6);   // b*MSEG + m
    int b = blk >> 9, m = blk & (MSEG - 1);
    double xa = X[(size_t)b * NPADC + (size_t)m * LSEG + lane];
    double ud0a = (double)U[((size_t)0 * NPADC + (size_t)m * LSEG + lane) * BCH + b];
    double ud1a = (double)U[((size_t)1 * NPADC + (size_t)m * LSEG + lane) * BCH + b];
    double c;
    if (m + 1 == MSEG) {
        c = (lane == 0) ? 1.0 : 0.0;
    } else {
        double a  = (lane < KP) ? sfxI[((size_t)b * MSEG + m + 1) * KP + lane] : 0.0;
        double cg = (lane < KP) ? gcarry[((size_t)b * NG + (m + 1) / GSZ) * KP + lane] : 0.0;
        c = conv33_rb(cg, a);             // same op order as round-7 k_chkpt
        c = (lane < KP) ? c : 0.0;        // keep lanes>=33 identical to prior rounds
    }
    int S0 = lane, S1 = lane;
    unsigned long long mk0 = 0, mk1 = 0;
#pragma unroll
    for (int j = LSEG - 1; j >= 0; --j) {
        double xj = readlane_d(xa, j);
        double up = dpp_shr1_d(c);                   // sfx[j+1][lane-1], lane0 -> 0
        double rhs = xj * up;
        double cn = fma(xj, up, c);                  // sfx[j][lane]
        double ud0 = readlane_d(ud0a, j);            // pre-converted, bit-identical
        double ud1 = readlane_d(ud1a, j);
        bool i0 = (ud0 * cn < rhs);                  // lane0: rhs==0 -> false
        bool i1 = (ud1 * cn < rhs);
        unsigned long long b0 = __ballot(i0);
        unsigned long long b1 = __ballot(i1);
        if (lane == j) { mk0 = b0; mk1 = b1; }       // SGPR->VGPR cndmask, no LDS
        int t0 = dpp_shr1_i(S0);
        int t1 = dpp_shr1_i(S1);
        if (i0) S0 = t0;
        if (i1) S1 = t1;
        c = cn;
    }
    size_t sb0 = (size_t)blk;
    size_t sb1 = (size_t)BCH * MSEG + blk;
    masks[sb0 * LSEG + lane] = mk0;
    masks[sb1 * LSEG + lane] = mk1;
    if (lane < KP) {
        tab[sb0 * KP + lane] = S0;
        tab[sb1 * KP + lane] = S1;
    }
}

// ---- kernel 5: hierarchical compose; per-wave tables kept in VGPRs
__global__ void __launch_bounds__(1024) k_compose(const int* __restrict__ tab,
                                                  int* __restrict__ rent) {
    __shared__ int gtab[NG][KP];
    __shared__ int gent[NG];
    int sb = blockIdx.x;                  // s*BCH + b
    int tid = threadIdx.x;                // 1024
    int w = tid >> 6, lane = tid & 63;
    int tv[GSZ];
    const int* base = tab + ((size_t)sb * MSEG + w * GSZ) * KP;
#pragma unroll
    for (int i = 0; i < GSZ; ++i)
        tv[i] = (lane < KP) ? base[i * KP + lane] : 0;
    int T = lane;                         // compose this wave's 32 segment maps
#pragma unroll
    for (int i = 0; i < GSZ; ++i)
        T = __shfl(tv[i], T, 64);
    if (lane < KP) gtab[w][lane] = T;
    __syncthreads();
    if (tid == 0) {
        int r = KK;
        for (int g = 0; g < NG; ++g) { gent[g] = r; r = gtab[g][r]; }
    }
    __syncthreads();
    int r = __builtin_amdgcn_readfirstlane(gent[w]);
    int rv = 0;
#pragma unroll
    for (int i = 0; i < GSZ; ++i) {       // scalar walk via readlane (no LDS chain)
        if (lane == i) rv = r;
        r = __builtin_amdgcn_readlane(tv[i], r);
    }
    if (lane < GSZ) rent[(size_t)sb * MSEG + w * GSZ + lane] = rv;
}

// ---- kernel 6: replay masks -> packed bitset, PLUS independent marginal rows
//      blockIdx.x < SS*BCH*MSEG/4 : replay (4 segments / block)
//      else                       : one marginal output row per block
__global__ void k_repmarg(const unsigned long long* __restrict__ masks,
                          const int* __restrict__ rent,
                          const double* __restrict__ X, const double* __restrict__ eZ,
                          unsigned long long* __restrict__ bitflat,
                          float* __restrict__ outMarg) {
    __shared__ double e[KP];
    __shared__ double invZ;
    const int NREP = SS * BCH * MSEG / 4;            // 8192 replay blocks
    if (blockIdx.x < NREP) {
        int lane = threadIdx.x & 63;
        int blk = blockIdx.x * 4 + (threadIdx.x >> 6);   // sb*MSEG + m
        unsigned long long mv = masks[(size_t)blk * LSEG + lane];
        int mlo = (int)(unsigned)mv;
        int mhi = (int)(unsigned)(mv >> 32);
        int r = __builtin_amdgcn_readfirstlane(rent[blk]);
        unsigned long long sel = 0;
#pragma unroll
        for (int j = 0; j < LSEG; ++j) {
            unsigned lo = (unsigned)__builtin_amdgcn_readlane(mlo, j);
            unsigned hi = (unsigned)__builtin_amdgcn_readlane(mhi, j);
            unsigned long long mj = ((unsigned long long)hi << 32) | lo;
            int inc = (int)((mj >> r) & 1ull);
            sel |= ((unsigned long long)inc) << j;
            r -= inc;
        }
        if (lane == 0) bitflat[blk] = sel;
    } else {
        int q = blockIdx.x - NREP;                   // b*NMAXC + i
        int b = q >> 8, i = q & (NMAXC - 1);
        int j = threadIdx.x;                         // 256
        if (j < KP) e[j] = eZ[(size_t)b * KP + j];
        __syncthreads();
        if (j == 0) invZ = 1.0 / e[KK];
        __syncthreads();
        float v = 0.0f;
        if (i != j) {
            int t = (j > i) ? (OFFS(i) + j - i - 1) : (OFFS(j) + i - j - 1);
            double x = X[(size_t)b * NPADC + t];
            double f = 1.0;
#pragma unroll
            for (int k = 1; k < KK; ++k) f = fma(-x, f, e[k]);
            v = (float)(x * f * invZ);
        }
        outMarg[((size_t)b * NMAXC + i) * NMAXC + j] = v;
    }
}

// ---- kernel 7: mask emission, float4 stores; 4 rows / block
__global__ void k_emitmask(const unsigned long long* __restrict__ bitflat,
                           float* __restrict__ outMask) {
    __shared__ unsigned long long bf[MSEG];
    int sb = blockIdx.y;
    int tid = threadIdx.x;                // 256
    bf[tid] = bitflat[(size_t)sb * MSEG + tid];
    bf[tid + 256] = bitflat[(size_t)sb * MSEG + 256 + tid];
    __syncthreads();
    int i = blockIdx.x * 4 + (tid >> 6);  // row
    int lane = tid & 63;
    float4 v4;
    float* pv = (float*)&v4;
#pragma unroll
    for (int jj = 0; jj < 4; ++jj) {
        int j = lane * 4 + jj;
        float v = 0.0f;
        if (j > i) {
            int t = OFFS(i) + j - i - 1;
            v = (float)((bf[t >> 6] >> (t & 63)) & 1ull);
        } else if (j < i) {
            int t = OFFS(j) + i - j - 1;
            v = (float)((bf[t >> 6] >> (t & 63)) & 1ull);
        }
        pv[jj] = v;
    }
    *reinterpret_cast<float4*>(&outMask[((size_t)sb * NMAXC + i) * NMAXC + lane * 4]) = v4;
}

extern "C" void kernel_launch(void* const* d_in, const int* in_sizes, int n_in,
                              void* d_out, int out_size, void* d_ws, size_t ws_size,
                              hipStream_t stream) {
    const float* scores = (const float*)d_in[0];
    const float* uniforms = (const float*)d_in[1];

    char* ws = (char*)d_ws;
    size_t off = 0;
    auto alloc = [&](size_t bytes) {
        void* p = ws + off;
        off += (bytes + 255) & ~(size_t)255;
        return p;
    };
    double* X      = (double*)alloc((size_t)BCH * NPADC * 8);
    double* Bp     = (double*)alloc((size_t)BCH * MSEG * KP * 8);
    double* sfxI   = (double*)alloc((size_t)BCH * MSEG * KP * 8);
    double* gpoly  = (double*)alloc((size_t)BCH * NG * KP * 8);
    double* gcarry = (double*)alloc((size_t)BCH * NG * KP * 8);
    double* eZ     = (double*)alloc((size_t)BCH * KP * 8);
    unsigned long long* masks = (unsigned long long*)alloc((size_t)SS * BCH * MSEG * LSEG * 8);
    int* tab       = (int*)alloc((size_t)SS * BCH * MSEG * KP * 4);
    int* rent      = (int*)alloc((size_t)SS * BCH * MSEG * 4);
    unsigned long long* bitflat = (unsigned long long*)alloc((size_t)SS * BCH * MSEG * 8);
    if (off > ws_size) return;            // ~38 MB

    float* outMask = (float*)d_out;
    float* outMarg = (float*)d_out + (size_t)SS * BCH * NMAXC * NMAXC;

    k_prep<<<BCH * MSEG / 4, 256, 0, stream>>>(scores, X, Bp);
    k_gpart<<<BCH * NG, 64, 0, stream>>>(Bp, sfxI, gpoly);
    k_gscan<<<BCH, 64, 0, stream>>>(gpoly, gcarry, eZ);
    k_backward<<<BCH * MSEG / 4, 256, 0, stream>>>(X, sfxI, gcarry, uniforms, masks, tab);
    k_compose<<<SS * BCH, 1024, 0, stream>>>(tab, rent);
    k_repmarg<<<SS * BCH * MSEG / 4 + BCH * NMAXC, 256, 0, stream>>>(
        masks, rent, X, eZ, bitflat, outMarg);
    k_emitmask<<<dim3(NMAXC / 4, SS * BCH), 256, 0, stream>>>(bitflat, outMask);
}

// Round 12
// 130.311 us; speedup vs baseline: 7.8363x; 1.2037x over previous
//
#include <hip/hip_runtime.h>

#define KK 32
#define KP 33
#define NMAXC 256
#define BCH 32            // bsz * ENS
#define NPADC 32768
#define TARGETC 32640
#define LSEG 64           // items per segment
#define MSEG 512          // NPADC / LSEG
#define GSZ 32            // segments per group
#define NG 16             // MSEG / GSZ
#define SS 2

#define OFFS(i) ((i)*255 - (i)*((i)-1)/2)

// ---- cross-lane helpers on the VALU pipe (no ds_bpermute) ----
__device__ __forceinline__ int dpp_shr1_i(int v) {
    // wave_shr:1 (0x138), bound_ctrl=1 -> lane 0 receives 0
    return __builtin_amdgcn_mov_dpp(v, 0x138, 0xf, 0xf, true);
}
__device__ __forceinline__ double dpp_shr1_d(double v) {
    union { double d; int i[2]; } u; u.d = v;
    u.i[0] = dpp_shr1_i(u.i[0]);
    u.i[1] = dpp_shr1_i(u.i[1]);
    return u.d;
}
__device__ __forceinline__ unsigned long long dpp_shr1_ull(unsigned long long v) {
    union { unsigned long long q; int i[2]; } u; u.q = v;
    u.i[0] = dpp_shr1_i(u.i[0]);
    u.i[1] = dpp_shr1_i(u.i[1]);
    return u.q;
}
__device__ __forceinline__ double readlane_d(double v, int l) {
    union { double d; int i[2]; } u; u.d = v;
    union { double d; int i[2]; } r;
    r.i[0] = __builtin_amdgcn_readlane(u.i[0], l);
    r.i[1] = __builtin_amdgcn_readlane(u.i[1], l);
    return r.d;
}

__device__ __forceinline__ void decode_ij(int t, int& oi, int& oj) {
    int ii = (int)((511.0 - sqrt(511.0 * 511.0 - 8.0 * (double)t)) * 0.5);
    if (ii < 0) ii = 0;
    if (ii > 254) ii = 254;
    while (ii < 254 && OFFS(ii + 1) <= t) ++ii;
    while (ii > 0 && OFFS(ii) > t) --ii;
    oi = ii;
    oj = t - OFFS(ii) + ii + 1;
}

// 33-point truncated polynomial product: out[r] = sum_j a[j]*b[r-j].
// a read via readlane (dependent operand), b rotated via DPP (independent).
__device__ __forceinline__ double conv33_rb(double a_dep, double b_rot) {
    double s0 = 0.0, s1 = 0.0, s2 = 0.0, s3 = 0.0;
    double brot = b_rot;
#pragma unroll
    for (int j = 0; j < KP; ++j) {
        double aj = readlane_d(a_dep, j);
        switch (j & 3) {
            case 0: s0 = fma(aj, brot, s0); break;
            case 1: s1 = fma(aj, brot, s1); break;
            case 2: s2 = fma(aj, brot, s2); break;
            default: s3 = fma(aj, brot, s3); break;
        }
        brot = dpp_shr1_d(brot);
    }
    return (s0 + s1) + (s2 + s3);
}

// ---- kernel 1: fused exp(theta) + per-segment elementary symmetric polys
__global__ void k_prep(const float* __restrict__ sc, double* __restrict__ X,
                       double* __restrict__ Bp) {
    int lane = threadIdx.x & 63;
    int blk = blockIdx.x * 4 + (threadIdx.x >> 6);   // b*MSEG + m
    int b = blk >> 9, m = blk & (MSEG - 1);
    int t = m * LSEG + lane;
    double x = 0.0;
    if (t < TARGETC) {
        int i, j;
        decode_ij(t, i, j);
        double th = (double)sc[((size_t)b * NMAXC + i) * NMAXC + j] +
                    (double)sc[((size_t)b * NMAXC + j) * NMAXC + i];
        x = exp(th);
    }
    X[(size_t)b * NPADC + t] = x;
    double c = (lane == 0) ? 1.0 : 0.0;
#pragma unroll
    for (int j = 0; j < LSEG; ++j) {
        double xj = readlane_d(x, j);
        double up = dpp_shr1_d(c);                   // lane0 -> 0
        c = fma(xj, up, c);
    }
    if (lane < KP) Bp[(size_t)blk * KP + lane] = c;
}

// ---- kernel 2: suffix-inclusive scan within group (1 wave/block, 512 blocks)
__global__ void k_gpart(const double* __restrict__ Bp,
                        double* __restrict__ sfxI, double* __restrict__ gpoly) {
    int lane = threadIdx.x;
    int blk = blockIdx.x;                 // b*NG + g
    int b = blk / NG, g = blk % NG;
    double run = (lane == 0) ? 1.0 : 0.0;
    int m = g * GSZ + (GSZ - 1);
    double bp = (lane < KP) ? Bp[((size_t)b * MSEG + m) * KP + lane] : 0.0;
    for (int i = GSZ - 1; i >= 0; --i) {
        int mi = g * GSZ + i;
        double bpn = (i > 0 && lane < KP) ? Bp[((size_t)b * MSEG + mi - 1) * KP + lane] : 0.0;
        run = conv33_rb(run, bp);         // dependent operand via readlane
        if (lane < KP) sfxI[((size_t)b * MSEG + mi) * KP + lane] = run;
        bp = bpn;
    }
    if (lane < KP) gpoly[(size_t)blk * KP + lane] = run;
}

// ---- kernel 3: suffix scan over group polys (exclusive carries) + full Z poly
__global__ void k_gscan(const double* __restrict__ gpoly, double* __restrict__ gcarry,
                        double* __restrict__ eZ) {
    int lane = threadIdx.x;
    int b = blockIdx.x;
    double run = (lane == 0) ? 1.0 : 0.0;
    double gp = (lane < KP) ? gpoly[((size_t)b * NG + NG - 1) * KP + lane] : 0.0;
    for (int g = NG - 1; g >= 0; --g) {
        if (lane < KP) gcarry[((size_t)b * NG + g) * KP + lane] = run;
        double gpn = (g > 0 && lane < KP) ? gpoly[((size_t)b * NG + g - 1) * KP + lane] : 0.0;
        run = conv33_rb(run, gp);
        gp = gpn;
    }
    if (lane < KP) eZ[(size_t)b * KP + lane] = run;   // e_0..e_K of all items
}

// ---- kernel 4: backward sfx sweep fused with sampling.
//      Composes the per-entry-state SELECTION BITSET map B(s) directly:
//      B_new(s) = inc(s) ? (B_old(s-1) | 1<<j) : B_old(s).
//      Exit-state table tab(s) = s - popcount(B(s)) (epilogue).
__global__ void k_backward(const double* __restrict__ X, const double* __restrict__ sfxI,
                           const double* __restrict__ gcarry, const float* __restrict__ U,
                           unsigned long long* __restrict__ masks, int* __restrict__ tab) {
    int lane = threadIdx.x & 63;
    int blk = blockIdx.x * 4 + (threadIdx.x >> 6);   // b*MSEG + m
    int b = blk >> 9, m = blk & (MSEG - 1);
    double xa = X[(size_t)b * NPADC + (size_t)m * LSEG + lane];
    double ud0a = (double)U[((size_t)0 * NPADC + (size_t)m * LSEG + lane) * BCH + b];
    double ud1a = (double)U[((size_t)1 * NPADC + (size_t)m * LSEG + lane) * BCH + b];
    double c;
    if (m + 1 == MSEG) {
        c = (lane == 0) ? 1.0 : 0.0;
    } else {
        double a  = (lane < KP) ? sfxI[((size_t)b * MSEG + m + 1) * KP + lane] : 0.0;
        double cg = (lane < KP) ? gcarry[((size_t)b * NG + (m + 1) / GSZ) * KP + lane] : 0.0;
        c = conv33_rb(cg, a);             // same op order as round-7 k_chkpt
        c = (lane < KP) ? c : 0.0;        // keep lanes>=33 identical to prior rounds
    }
    unsigned long long B0 = 0, B1 = 0;
#pragma unroll
    for (int j = LSEG - 1; j >= 0; --j) {
        double xj = readlane_d(xa, j);
        double up = dpp_shr1_d(c);                   // sfx[j+1][lane-1], lane0 -> 0
        double rhs = xj * up;
        double cn = fma(xj, up, c);                  // sfx[j][lane]
        double ud0 = readlane_d(ud0a, j);
        double ud1 = readlane_d(ud1a, j);
        bool i0 = (ud0 * cn < rhs);                  // lane0: rhs==0 -> false
        bool i1 = (ud1 * cn < rhs);
        unsigned long long bit = 1ull << j;
        unsigned long long s0 = dpp_shr1_ull(B0) | bit;
        unsigned long long s1 = dpp_shr1_ull(B1) | bit;
        if (i0) B0 = s0;
        if (i1) B1 = s1;
        c = cn;
    }
    size_t sb0 = (size_t)blk;
    size_t sb1 = (size_t)BCH * MSEG + blk;
    masks[sb0 * LSEG + lane] = B0;                   // state-major realized bitsets
    masks[sb1 * LSEG + lane] = B1;
    if (lane < KP) {
        int S0 = lane - (__popc((unsigned)B0) + __popc((unsigned)(B0 >> 32)));
        int S1 = lane - (__popc((unsigned)B1) + __popc((unsigned)(B1 >> 32)));
        tab[sb0 * KP + lane] = S0;
        tab[sb1 * KP + lane] = S1;
    }
}

// ---- kernel 5: hierarchical compose; per-wave tables kept in VGPRs
__global__ void __launch_bounds__(1024) k_compose(const int* __restrict__ tab,
                                                  int* __restrict__ rent) {
    __shared__ int gtab[NG][KP];
    __shared__ int gent[NG];
    int sb = blockIdx.x;                  // s*BCH + b
    int tid = threadIdx.x;                // 1024
    int w = tid >> 6, lane = tid & 63;
    int tv[GSZ];
    const int* base = tab + ((size_t)sb * MSEG + w * GSZ) * KP;
#pragma unroll
    for (int i = 0; i < GSZ; ++i)
        tv[i] = (lane < KP) ? base[i * KP + lane] : 0;
    int T = lane;                         // compose this wave's 32 segment maps
#pragma unroll
    for (int i = 0; i < GSZ; ++i)
        T = __shfl(tv[i], T, 64);
    if (lane < KP) gtab[w][lane] = T;
    __syncthreads();
    if (tid == 0) {
        int r = KK;
        for (int g = 0; g < NG; ++g) { gent[g] = r; r = gtab[g][r]; }
    }
    __syncthreads();
    int r = __builtin_amdgcn_readfirstlane(gent[w]);
    int rv = 0;
#pragma unroll
    for (int i = 0; i < GSZ; ++i) {       // scalar walk via readlane (no LDS chain)
        if (lane == i) rv = r;
        r = __builtin_amdgcn_readlane(tv[i], r);
    }
    if (lane < GSZ) rent[(size_t)sb * MSEG + w * GSZ + lane] = rv;
}

// ---- kernel 6: combined emission; replay absorbed as a gather.
//      blockIdx.x < 64 : mask rows (sb = blockIdx.y, 4 rows, float4 stores)
//      blockIdx.x >= 64: marginal row (b = y>>1, i = (y&1)*128 + x-64)
__global__ void k_emit(const unsigned long long* __restrict__ masks,
                       const int* __restrict__ rent,
                       const double* __restrict__ X, const double* __restrict__ eZ,
                       float* __restrict__ outMask, float* __restrict__ outMarg) {
    __shared__ unsigned long long bf[MSEG];
    __shared__ double e[KP];
    __shared__ double invZ;
    int x = blockIdx.x, y = blockIdx.y;
    int tid = threadIdx.x;                // 256
    if (x < NMAXC / 4) {
        int sb = y;
        int s0 = tid, s1 = tid + 256;
        bf[s0] = masks[((size_t)sb * MSEG + s0) * LSEG + rent[(size_t)sb * MSEG + s0]];
        bf[s1] = masks[((size_t)sb * MSEG + s1) * LSEG + rent[(size_t)sb * MSEG + s1]];
        __syncthreads();
        int i = x * 4 + (tid >> 6);
        int lane = tid & 63;
        float4 v4;
        float* pv = (float*)&v4;
#pragma unroll
        for (int jj = 0; jj < 4; ++jj) {
            int j = lane * 4 + jj;
            float v = 0.0f;
            if (j > i) {
                int t = OFFS(i) + j - i - 1;
                v = (float)((bf[t >> 6] >> (t & 63)) & 1ull);
            } else if (j < i) {
                int t = OFFS(j) + i - j - 1;
                v = (float)((bf[t >> 6] >> (t & 63)) & 1ull);
            }
            pv[jj] = v;
        }
        *reinterpret_cast<float4*>(&outMask[((size_t)sb * NMAXC + i) * NMAXC + lane * 4]) = v4;
    } else {
        int b = y >> 1;
        int i = (y & 1) * 128 + (x - NMAXC / 4);
        int j = tid;
        if (j < KP) e[j] = eZ[(size_t)b * KP + j];
        __syncthreads();
        if (j == 0) invZ = 1.0 / e[KK];
        __syncthreads();
        float v = 0.0f;
        if (i != j) {
            int t = (j > i) ? (OFFS(i) + j - i - 1) : (OFFS(j) + i - j - 1);
            double xv = X[(size_t)b * NPADC + t];
            double f = 1.0;
#pragma unroll
            for (int k = 1; k < KK; ++k) f = fma(-xv, f, e[k]);
            v = (float)(xv * f * invZ);
        }
        outMarg[((size_t)b * NMAXC + i) * NMAXC + j] = v;
    }
}

extern "C" void kernel_launch(void* const* d_in, const int* in_sizes, int n_in,
                              void* d_out, int out_size, void* d_ws, size_t ws_size,
                              hipStream_t stream) {
    const float* scores = (const float*)d_in[0];
    const float* uniforms = (const float*)d_in[1];

    char* ws = (char*)d_ws;
    size_t off = 0;
    auto alloc = [&](size_t bytes) {
        void* p = ws + off;
        off += (bytes + 255) & ~(size_t)255;
        return p;
    };
    double* X      = (double*)alloc((size_t)BCH * NPADC * 8);
    double* Bp     = (double*)alloc((size_t)BCH * MSEG * KP * 8);
    double* sfxI   = (double*)alloc((size_t)BCH * MSEG * KP * 8);
    double* gpoly  = (double*)alloc((size_t)BCH * NG * KP * 8);
    double* gcarry = (double*)alloc((size_t)BCH * NG * KP * 8);
    double* eZ     = (double*)alloc((size_t)BCH * KP * 8);
    unsigned long long* masks = (unsigned long long*)alloc((size_t)SS * BCH * MSEG * LSEG * 8);
    int* tab       = (int*)alloc((size_t)SS * BCH * MSEG * KP * 4);
    int* rent      = (int*)alloc((size_t)SS * BCH * MSEG * 4);
    if (off > ws_size) return;            // ~37 MB

    float* outMask = (float*)d_out;
    float* outMarg = (float*)d_out + (size_t)SS * BCH * NMAXC * NMAXC;

    k_prep<<<BCH * MSEG / 4, 256, 0, stream>>>(scores, X, Bp);
    k_gpart<<<BCH * NG, 64, 0, stream>>>(Bp, sfxI, gpoly);
    k_gscan<<<BCH, 64, 0, stream>>>(gpoly, gcarry, eZ);
    k_backward<<<BCH * MSEG / 4, 256, 0, stream>>>(X, sfxI, gcarry, uniforms, masks, tab);
    k_compose<<<SS * BCH, 1024, 0, stream>>>(tab, rent);
    k_emit<<<dim3(NMAXC / 4 + 128, SS * BCH), 256, 0, stream>>>(
        masks, rent, X, eZ, outMask, outMarg);
}